// Round 2
// baseline (1391.338 us; speedup 1.0000x reference)
//
#include <hip/hip_runtime.h>
#include <stdint.h>

// Net_11587821765063: sequential SNN scan, T=1000 steps.
// Output = spike_out (T,1,COUT) float32 only; w / traces are not returned.
//
// Round 21 (session r1): round-20 structure, workspace layout reverted to the
// PROVEN r19 envelope (single packed code buffer, 16B per (t,lane), byte =
// x | (p<<1), offsets unchanged, total 1,548,288 B) to eliminate the only
// hard-risk delta of r20 (possible ws overrun -> container abort).
// Kept from r20:
//  - gather (gv) PREFETCHED one iteration ahead (issued right after publish),
//    consumed next iter -> no vmcnt(0) store-ack drain, agent-load latency
//    hidden under a full step of independent work.
//  - grid 256 blocks x 128 threads (2 waves/block) -> all 256 CUs active,
//    halves per-CU issue/LDS/L1 contention (was 128 blocks = half chip idle).
//  - main loop unrolled x2 with swapped register sets -> no rotate movs.
// Bit-exact invariants preserved verbatim: per-lane 13-FMA dot order, the
// validated 32/16/8/4/2/1 xor butterfly pairing, hypothesis & update math,
// publish byte format (0xB0 | hb), scan8 semantics, retry loop.

#define T_STEPS 1000
#define CIN     784
#define COUT    512
#define CPL     13            // columns per lane (64*13 = 832 >= 784)
#define NROW    512           // one publish byte per row per step
#define VTHR_F   12500.0f
#define PROHIB_F 11250.0f

#define SLOTS_BYTES (T_STEPS * NROW)          // 512000 B
#define CODE_OFFSET 524288                    // 512 KiB >= 512000 B of slots

// ---- prep: zero slot bytes and pack per-(t,lane) 16-byte code slot:
// byte j (j<13) encodes col = lane*13+j: bit0 = x[t][col], bits[2:1] = p.
__global__ __launch_bounds__(256) void prep_kernel(const int* __restrict__ x,
                                                   uint8_t* __restrict__ code,
                                                   uint2* __restrict__ slots2) {
    int gid = blockIdx.x * blockDim.x + threadIdx.x;   // one per (t, lane)
    if (gid >= T_STEPS * 64) return;
    slots2[gid] = make_uint2(0u, 0u);                  // 64000 x 8B = 512000 B
    int t = gid >> 6;
    int lane = gid & 63;
    uint32_t wds[4] = {0u, 0u, 0u, 0u};
    #pragma unroll
    for (int j = 0; j < CPL; ++j) {
        int col = lane * CPL + j;
        uint32_t b = 0u;
        if (col < CIN) {
            int xc = x[t * CIN + col];
            int xp = (t > 0) ? x[(t - 1) * CIN + col] : 0;
            int p = xc ? 2 : ((t == 0) ? 1 : (xp ? 1 : 0));
            b = (uint32_t)((xc & 1) | (p << 1));
        }
        wds[j >> 2] |= b << ((j & 3) * 8);
    }
    ((uint4*)code)[gid] = make_uint4(wds[0], wds[1], wds[2], wds[3]);
}

// scan one gathered uint64 (8 row-bytes): present = high nibble 0xB;
// set = present && hypothesis bit kk.
__device__ __forceinline__ void scan8(unsigned long long gv, int kk,
                                      bool& anyset, bool& allp) {
    anyset = false; allp = true;
    #pragma unroll
    for (int i = 0; i < 8; ++i) {
        uint32_t b = (uint32_t)(gv >> (8 * i)) & 0xFFu;
        bool p = (b & 0xF0u) == 0xB0u;
        allp = allp && p;
        anyset = anyset || (p && (((b >> kk) & 1u) != 0u));
    }
}

__device__ __forceinline__ void decode_code(const uint4& c, float* xf, float* pf) {
    uint32_t cwd[4] = {c.x, c.y, c.z, c.w};
    #pragma unroll
    for (int j = 0; j < CPL; ++j) {
        uint32_t byte = (cwd[j >> 2] >> ((j & 3) * 8)) & 0xFFu;
        xf[j] = (float)(byte & 1u);
        pf[j] = (float)(byte >> 1);
    }
}

// ---- fast bit-exact butterfly building blocks ----
typedef unsigned uint2ev __attribute__((ext_vector_type(2)));

__device__ __forceinline__ float pl32_sum(float v) {
    unsigned a = __builtin_bit_cast(unsigned, v);
    unsigned b = a;
#if __has_builtin(__builtin_amdgcn_permlane32_swap)
    uint2ev r = __builtin_amdgcn_permlane32_swap(a, b, false, false);
    a = r.x; b = r.y;
#else
    asm volatile("v_permlane32_swap_b32 %0, %1" : "+v"(a), "+v"(b));
#endif
    return __builtin_bit_cast(float, a) + __builtin_bit_cast(float, b);
}

__device__ __forceinline__ float pl16_sum(float v) {
    unsigned a = __builtin_bit_cast(unsigned, v);
    unsigned b = a;
#if __has_builtin(__builtin_amdgcn_permlane16_swap)
    uint2ev r = __builtin_amdgcn_permlane16_swap(a, b, false, false);
    a = r.x; b = r.y;
#else
    asm volatile("v_permlane16_swap_b32 %0, %1" : "+v"(a), "+v"(b));
#endif
    return __builtin_bit_cast(float, a) + __builtin_bit_cast(float, b);
}

template <int CTRL>
__device__ __forceinline__ float dpp_xor_sum(float v) {
    int xi = __builtin_bit_cast(int, v);
    int t = __builtin_amdgcn_update_dpp(xi, xi, CTRL, 0xF, 0xF, false);
    return v + __builtin_bit_cast(float, t);
}

__device__ __forceinline__ float swz4_sum(float v) {
    int xi = __builtin_bit_cast(int, v);
    int t = __builtin_amdgcn_ds_swizzle(xi, 0x101F);   // xor4
    return v + __builtin_bit_cast(float, t);
}

// full 64-lane sum, pairing bit-identical to the validated 32,16,8,4,2,1
// xor butterfly (adds commuted only -> bitwise-equal results)
__device__ __forceinline__ float wave_sum(float v) {
    v = pl32_sum(v);                  // stage 32
    v = pl16_sum(v);                  // stage 16
    v = dpp_xor_sum<0x128>(v);        // stage 8: row_ror:8 == xor8
    v = swz4_sum(v);                  // stage 4
    v = dpp_xor_sum<0x4E>(v);         // stage 2: quad_perm [2,3,0,1]
    v = dpp_xor_sum<0xB1>(v);         // stage 1: quad_perm [1,0,3,2]
    return v;                         // every lane holds the full sum
}

// one SNN step; fully inlined; pipeline registers passed explicitly so the
// x2-unrolled caller swaps roles instead of rotating (no movs).
__device__ __forceinline__ void snn_step(
    int u, int row, int lane,
    const uint4* __restrict__ code4, uint8_t* __restrict__ slots,
    float (&wA)[CPL], float (&wB)[CPL],
    float (&xfc)[CPL], float (&pfc)[CPL],     // decoded planes for step u
    float (&xfn)[CPL], float (&pfn)[CPL],     // decode target (step u+1)
    uint4& cwn,                               // in: raw code for step u+1
    uint4& cwl,                               // out: loaded code for u+2
    float& memA, float& memB, bool& psA, bool& psB,
    int& p2, int& p3, int& hb_m1, int& hb_m2,
    unsigned long long& gv_next, uint32_t& myb)
{
    // ---- issue code load for u+2 (consumed 2 steps later) ----
    cwl = (u + 2 < T_STEPS) ? code4[(size_t)(u + 2) * 64 + lane]
                            : make_uint4(0u, 0u, 0u, 0u);

    const int kk = (p3 << 1) | p2;                 // (P[u-3]<<1)|P[u-2]
    const bool selfdec = (u >= 2) && (((hb_m2 >> kk) & 1) != 0);

    // ---- dots for both branches (validated per-lane order) ----
    float dA = 0.0f, dB = 0.0f;
    #pragma unroll
    for (int j = 0; j < CPL; ++j) {
        dA += xfc[j] * wA[j];          // exact: x in {0,1}
        dB += xfc[j] * wB[j];
    }

    // ---- fast butterfly: two independent chains, bit-exact pairing ----
    float dotA = wave_sum(dA);
    float dotB = wave_sum(dB);

    // ---- pipelined decode of step u+1's codes (off the w->dot chain) ----
    decode_code(cwn, xfn, pfn);

    // ---- 4 hypotheses (d = P[u-1] branch, c = P[u] branch) ----
    float sa = memA + dotA;            // reference op order
    float sb = memB + dotB;
    float m00 = fmaxf(sa, 0.0f),            m01 = fmaxf(sa - PROHIB_F, 0.0f);
    float m10 = fmaxf(sb, 0.0f),            m11 = fmaxf(sb - PROHIB_F, 0.0f);
    bool s00 = m00 >= VTHR_F, s01 = m01 >= VTHR_F;
    bool s10 = m10 >= VTHR_F, s11 = m11 >= VTHR_F;
    int hb = (s00 ? 1 : 0) | (s01 ? 2 : 0) | (s10 ? 4 : 0) | (s11 ? 8 : 0);

    // ---- publish own row's hb(u) immediately (fire-and-forget byte) ----
    if (lane == 0)
        __hip_atomic_store(&slots[(size_t)u * NROW + row],
                           (uint8_t)(0xB0u | (uint32_t)hb),
                           __ATOMIC_RELAXED, __HIP_MEMORY_SCOPE_AGENT);

    // ---- prefetch next iter's gather: slots[(u+1)-2] = slots[u-1] ----
    // issued ~1 full step before consumption -> coherent-load latency hidden,
    // and the wait at consumption is counted (no store-ack drain).
    unsigned long long gv_new = 0ull;
    if (u >= 1) {
        const unsigned long long* glp =
            (const unsigned long long*)(slots + (size_t)(u - 1) * NROW);
        gv_new = __hip_atomic_load(&glp[lane], __ATOMIC_RELAXED,
                                   __HIP_MEMORY_SCOPE_AGENT);
    }

    // ---- resolve P[u-1]: own-row selfdec (~88%) or global fallback ----
    int bst = 0;
    if (u >= 2) {
        if (selfdec) {
            bst = 1;                   // own row spiked at u-2
        } else {
            const unsigned long long* gl =
                (const unsigned long long*)(slots + (size_t)(u - 2) * NROW);
            unsigned long long gv = gv_next;       // prefetched last iter
            for (;;) {
                bool anyset, allp;
                scan8(gv, kk, anyset, allp);
                if (__any((int)anyset)) { bst = 1; break; }
                if (__all((int)allp)) { bst = 0; break; }
                __builtin_amdgcn_s_sleep(1);       // backoff (rare path)
                gv = __hip_atomic_load(&gl[lane], __ATOMIC_RELAXED,
                                       __HIP_MEMORY_SCOPE_AGENT);
            }
        }
    }
    gv_next = gv_new;
    p3 = p2; p2 = bst;
    hb_m2 = hb_m1; hb_m1 = hb;

    // ---- collapse branch d=bst; record out bit; rebranch over c=P[u] ----
    bool sprv = bst ? psB : psA;                   // actual spike(u-1)
    bool sc0  = bst ? s10 : s00;                   // spike under c=0
    bool sc1  = bst ? s11 : s01;                   // spike under c=1
    float mc0 = bst ? m10 : m00;
    float mc1 = bst ? m11 : m01;

    if (u >= 1) {
        int v = u - 1;
        if ((v & 63) == lane) myb |= (sprv ? 1u : 0u) << (v >> 6);
    }

    memA = sc0 ? 0.0f : mc0;
    memB = sc1 ? 0.0f : mc1;

    // ---- merged if-converted updates (value-exact, no branches) ----
    float s0f = sc0 ? 1.0f : 0.0f;
    float s1f = sc1 ? 1.0f : 0.0f;
    float d0f = (!sc0 && sprv) ? 1.0f : 0.0f;      // mutually exclusive
    float d1f = (!sc1 && sprv) ? 1.0f : 0.0f;
    #pragma unroll
    for (int j = 0; j < CPL; ++j) {
        float base = bst ? wB[j] : wA[j];          // wB==wA when agreed
        float ta = fminf(fmaf(s0f, pfc[j], base), 127.0f);
        wA[j] = fmaxf(fmaf(-d0f, xfc[j], ta), 0.0f);
        float tb = fminf(fmaf(s1f, pfc[j], base), 127.0f);
        wB[j] = fmaxf(fmaf(-d1f, xfc[j], tb), 0.0f);
    }
    psA = sc0; psB = sc1;
}

__global__ __launch_bounds__(128, 1) void snn_kernel(const float* __restrict__ weight,
                                                     const uint8_t* __restrict__ code,
                                                     uint8_t* __restrict__ slots,
                                                     float* __restrict__ out) {
    const int tid  = threadIdx.x;
    const int wave = tid >> 6;
    const int lane = tid & 63;
    const int row  = blockIdx.x * 2 + wave;    // 512 autonomous waves, 256 CUs

    float wA[CPL], wB[CPL];
    #pragma unroll
    for (int j = 0; j < CPL; ++j) {
        int col = lane * CPL + j;
        float v = (col < CIN) ? weight[row * CIN + col] : 0.0f;
        wA[j] = v; wB[j] = v;
    }

    const uint4* code4 = (const uint4*)code;

    float xf0[CPL], pf0[CPL], xf1[CPL], pf1[CPL];
    {
        uint4 c0 = code4[lane];
        decode_code(c0, xf0, pf0);
    }
    uint4 cwA = code4[64 + lane];
    uint4 cwB = make_uint4(0u, 0u, 0u, 0u);

    float memA = 0.0f, memB = 0.0f;
    bool  psA = true, psB = true;          // spike(-1)=true quirk
    int p2 = 0, p3 = 0;                    // actual P[u-2], P[u-3]
    int hb_m1 = 0, hb_m2 = 0;              // own row hb(u-1), hb(u-2)
    unsigned long long gv_next = 0ull;     // prefetched gather
    uint32_t myb = 0u;                     // out bits: step v when v%64==lane

    for (int u = 0; u < T_STEPS; u += 2) {
        snn_step(u,     row, lane, code4, slots, wA, wB,
                 xf0, pf0, xf1, pf1, cwA, cwB,
                 memA, memB, psA, psB, p2, p3, hb_m1, hb_m2, gv_next, myb);
        snn_step(u + 1, row, lane, code4, slots, wA, wB,
                 xf1, pf1, xf0, pf0, cwB, cwA,
                 memA, memB, psA, psB, p2, p3, hb_m1, hb_m2, gv_next, myb);
    }

    // ---- epilogue: resolve P[T-1], record last bit, write this row's out ----
    // gv_next here holds the prefetch of slots[T-2] issued at u = T-1.
    {
        const int kk = (p3 << 1) | p2;
        int cst;
        if (((hb_m2 >> kk) & 1) != 0) {
            cst = 1;                       // own row forced the OR
        } else {
            const unsigned long long* gl2 =
                (const unsigned long long*)(slots + (size_t)(T_STEPS - 2) * NROW);
            unsigned long long gv2 = gv_next;
            for (;;) {
                bool anyset, allp;
                scan8(gv2, kk, anyset, allp);
                if (__any((int)anyset)) { cst = 1; break; }
                if (__all((int)allp)) { cst = 0; break; }
                __builtin_amdgcn_s_sleep(1);
                gv2 = __hip_atomic_load(&gl2[lane], __ATOMIC_RELAXED,
                                        __HIP_MEMORY_SCOPE_AGENT);
            }
        }
        bool sr = cst ? psB : psA;
        {
            int v = T_STEPS - 1;
            if ((v & 63) == lane) myb |= (sr ? 1u : 0u) << (v >> 6);
        }
        // write this row's 1000 spike floats from the bit register
        #pragma unroll
        for (int b = 0; b < 16; ++b) {
            int s = b * 64 + lane;
            if (s < T_STEPS)
                out[(size_t)s * COUT + row] = (float)((myb >> b) & 1u);
        }
    }
}

extern "C" void kernel_launch(void* const* d_in, const int* in_sizes, int n_in,
                              void* d_out, int out_size, void* d_ws, size_t ws_size,
                              hipStream_t stream) {
    const int*   x      = (const int*)d_in[0];     // (T,1,CIN) int32
    const float* weight = (const float*)d_in[1];   // (COUT,CIN) f32
    float* out = (float*)d_out;                    // (T,1,COUT) f32

    uint8_t* slots = (uint8_t*)d_ws;
    uint8_t* code  = (uint8_t*)d_ws + CODE_OFFSET;

    int prep_threads = T_STEPS * 64;
    prep_kernel<<<(prep_threads + 255) / 256, 256, 0, stream>>>(x, code,
                                                                (uint2*)slots);
    snn_kernel<<<256, 128, 0, stream>>>(weight, code, slots, out);
}

// Round 3
// 1010.671 us; speedup vs baseline: 1.3766x; 1.3766x over previous
//
#include <hip/hip_runtime.h>
#include <stdint.h>

// Net_11587821765063: sequential SNN scan, T=1000 steps.
// Output = spike_out (T,1,COUT) float32 only; w / traces are not returned.
//
// Round 22 (session r2): isolate the r21 regression. rocprof showed r21's
// distance-1 gather prefetch inserted an UNCONDITIONAL agent-scope RTT into
// every step (phi-copy of gv_next forced s_waitcnt vmcnt(0) right after the
// publish store -> ~1500+cy serial cost/step; FETCH doubled from retry
// storms). REVERTED the gather to the proven r19 form: issued top-of-step,
// gated on !selfdec (~88% of steps issue nothing), consumed mid-step under
// dot+butterfly cover, identical retry loop + epilogue.
// KEPT from r20/21 (not implicated by counters):
//  - grid 256 blocks x 128 threads (2 waves/block) -> all 256 CUs active,
//    halves per-CU issue contention (r19 ran 128 CUs at ~55% VALU issue).
//  - main loop unrolled x2 with swapped register sets -> no rotate movs.
// Bit-exact invariants preserved verbatim: per-lane 13-FMA dot order, the
// validated 32/16/8/4/2/1 xor butterfly pairing, hypothesis & update math,
// publish byte format (0xB0 | hb), scan8 semantics, retry loop.

#define T_STEPS 1000
#define CIN     784
#define COUT    512
#define CPL     13            // columns per lane (64*13 = 832 >= 784)
#define NROW    512           // one publish byte per row per step
#define VTHR_F   12500.0f
#define PROHIB_F 11250.0f

#define SLOTS_BYTES (T_STEPS * NROW)          // 512000 B
#define CODE_OFFSET 524288                    // 512 KiB >= 512000 B of slots

// ---- prep: zero slot bytes and pack per-(t,lane) 16-byte code slot:
// byte j (j<13) encodes col = lane*13+j: bit0 = x[t][col], bits[2:1] = p.
__global__ __launch_bounds__(256) void prep_kernel(const int* __restrict__ x,
                                                   uint8_t* __restrict__ code,
                                                   uint2* __restrict__ slots2) {
    int gid = blockIdx.x * blockDim.x + threadIdx.x;   // one per (t, lane)
    if (gid >= T_STEPS * 64) return;
    slots2[gid] = make_uint2(0u, 0u);                  // 64000 x 8B = 512000 B
    int t = gid >> 6;
    int lane = gid & 63;
    uint32_t wds[4] = {0u, 0u, 0u, 0u};
    #pragma unroll
    for (int j = 0; j < CPL; ++j) {
        int col = lane * CPL + j;
        uint32_t b = 0u;
        if (col < CIN) {
            int xc = x[t * CIN + col];
            int xp = (t > 0) ? x[(t - 1) * CIN + col] : 0;
            int p = xc ? 2 : ((t == 0) ? 1 : (xp ? 1 : 0));
            b = (uint32_t)((xc & 1) | (p << 1));
        }
        wds[j >> 2] |= b << ((j & 3) * 8);
    }
    ((uint4*)code)[gid] = make_uint4(wds[0], wds[1], wds[2], wds[3]);
}

// scan one gathered uint64 (8 row-bytes): present = high nibble 0xB;
// set = present && hypothesis bit kk.
__device__ __forceinline__ void scan8(unsigned long long gv, int kk,
                                      bool& anyset, bool& allp) {
    anyset = false; allp = true;
    #pragma unroll
    for (int i = 0; i < 8; ++i) {
        uint32_t b = (uint32_t)(gv >> (8 * i)) & 0xFFu;
        bool p = (b & 0xF0u) == 0xB0u;
        allp = allp && p;
        anyset = anyset || (p && (((b >> kk) & 1u) != 0u));
    }
}

__device__ __forceinline__ void decode_code(const uint4& c, float* xf, float* pf) {
    uint32_t cwd[4] = {c.x, c.y, c.z, c.w};
    #pragma unroll
    for (int j = 0; j < CPL; ++j) {
        uint32_t byte = (cwd[j >> 2] >> ((j & 3) * 8)) & 0xFFu;
        xf[j] = (float)(byte & 1u);
        pf[j] = (float)(byte >> 1);
    }
}

// ---- fast bit-exact butterfly building blocks ----
typedef unsigned uint2ev __attribute__((ext_vector_type(2)));

__device__ __forceinline__ float pl32_sum(float v) {
    unsigned a = __builtin_bit_cast(unsigned, v);
    unsigned b = a;
#if __has_builtin(__builtin_amdgcn_permlane32_swap)
    uint2ev r = __builtin_amdgcn_permlane32_swap(a, b, false, false);
    a = r.x; b = r.y;
#else
    asm volatile("v_permlane32_swap_b32 %0, %1" : "+v"(a), "+v"(b));
#endif
    return __builtin_bit_cast(float, a) + __builtin_bit_cast(float, b);
}

__device__ __forceinline__ float pl16_sum(float v) {
    unsigned a = __builtin_bit_cast(unsigned, v);
    unsigned b = a;
#if __has_builtin(__builtin_amdgcn_permlane16_swap)
    uint2ev r = __builtin_amdgcn_permlane16_swap(a, b, false, false);
    a = r.x; b = r.y;
#else
    asm volatile("v_permlane16_swap_b32 %0, %1" : "+v"(a), "+v"(b));
#endif
    return __builtin_bit_cast(float, a) + __builtin_bit_cast(float, b);
}

template <int CTRL>
__device__ __forceinline__ float dpp_xor_sum(float v) {
    int xi = __builtin_bit_cast(int, v);
    int t = __builtin_amdgcn_update_dpp(xi, xi, CTRL, 0xF, 0xF, false);
    return v + __builtin_bit_cast(float, t);
}

__device__ __forceinline__ float swz4_sum(float v) {
    int xi = __builtin_bit_cast(int, v);
    int t = __builtin_amdgcn_ds_swizzle(xi, 0x101F);   // xor4
    return v + __builtin_bit_cast(float, t);
}

// full 64-lane sum, pairing bit-identical to the validated 32,16,8,4,2,1
// xor butterfly (adds commuted only -> bitwise-equal results)
__device__ __forceinline__ float wave_sum(float v) {
    v = pl32_sum(v);                  // stage 32
    v = pl16_sum(v);                  // stage 16
    v = dpp_xor_sum<0x128>(v);        // stage 8: row_ror:8 == xor8
    v = swz4_sum(v);                  // stage 4
    v = dpp_xor_sum<0x4E>(v);         // stage 2: quad_perm [2,3,0,1]
    v = dpp_xor_sum<0xB1>(v);         // stage 1: quad_perm [1,0,3,2]
    return v;                         // every lane holds the full sum
}

// one SNN step; fully inlined; pipeline registers passed explicitly so the
// x2-unrolled caller swaps roles instead of rotating (no movs).
__device__ __forceinline__ void snn_step(
    int u, int row, int lane,
    const uint4* __restrict__ code4, uint8_t* __restrict__ slots,
    float (&wA)[CPL], float (&wB)[CPL],
    float (&xfc)[CPL], float (&pfc)[CPL],     // decoded planes for step u
    float (&xfn)[CPL], float (&pfn)[CPL],     // decode target (step u+1)
    uint4& cwn,                               // in: raw code for step u+1
    uint4& cwl,                               // out: loaded code for u+2
    float& memA, float& memB, bool& psA, bool& psB,
    int& p2, int& p3, int& hb_m1, int& hb_m2,
    uint32_t& myb)
{
    // ---- top-of-loop issues: code load for u+2, gated gather for u-2 ----
    cwl = (u + 2 < T_STEPS) ? code4[(size_t)(u + 2) * 64 + lane]
                            : make_uint4(0u, 0u, 0u, 0u);
    const int kk = (p3 << 1) | p2;                 // (P[u-3]<<1)|P[u-2]
    const bool selfdec = (u >= 2) && (((hb_m2 >> kk) & 1) != 0);
    const unsigned long long* gl =
        (const unsigned long long*)(slots + (size_t)(u >= 2 ? u - 2 : 0) * NROW);
    unsigned long long gv = 0xB0B0B0B0B0B0B0B0ull; // sentinel-passing dummy
    if (u >= 2 && !selfdec)
        gv = __hip_atomic_load(&gl[lane], __ATOMIC_RELAXED,
                               __HIP_MEMORY_SCOPE_AGENT);

    // ---- dots for both branches (validated per-lane order) ----
    float dA = 0.0f, dB = 0.0f;
    #pragma unroll
    for (int j = 0; j < CPL; ++j) {
        dA += xfc[j] * wA[j];          // exact: x in {0,1}
        dB += xfc[j] * wB[j];
    }

    // ---- fast butterfly: two independent chains, bit-exact pairing ----
    float dotA = wave_sum(dA);
    float dotB = wave_sum(dB);

    // ---- pipelined decode of step u+1's codes (off the w->dot chain) ----
    decode_code(cwn, xfn, pfn);

    // ---- 4 hypotheses (d = P[u-1] branch, c = P[u] branch) ----
    float sa = memA + dotA;            // reference op order
    float sb = memB + dotB;
    float m00 = fmaxf(sa, 0.0f),            m01 = fmaxf(sa - PROHIB_F, 0.0f);
    float m10 = fmaxf(sb, 0.0f),            m11 = fmaxf(sb - PROHIB_F, 0.0f);
    bool s00 = m00 >= VTHR_F, s01 = m01 >= VTHR_F;
    bool s10 = m10 >= VTHR_F, s11 = m11 >= VTHR_F;
    int hb = (s00 ? 1 : 0) | (s01 ? 2 : 0) | (s10 ? 4 : 0) | (s11 ? 8 : 0);

    // ---- publish own row's hb(u) immediately (fire-and-forget byte) ----
    if (lane == 0)
        __hip_atomic_store(&slots[(size_t)u * NROW + row],
                           (uint8_t)(0xB0u | (uint32_t)hb),
                           __ATOMIC_RELAXED, __HIP_MEMORY_SCOPE_AGENT);

    // ---- resolve P[u-1]: own-row selfdec (~88%) or global fallback ----
    int bst = 0;
    if (u >= 2) {
        if (selfdec) {
            bst = 1;                   // own row spiked at u-2
        } else {
            for (;;) {
                bool anyset, allp;
                scan8(gv, kk, anyset, allp);
                if (__any((int)anyset)) { bst = 1; break; }
                if (__all((int)allp)) { bst = 0; break; }
                __builtin_amdgcn_s_sleep(1);       // backoff (rare path)
                gv = __hip_atomic_load(&gl[lane], __ATOMIC_RELAXED,
                                       __HIP_MEMORY_SCOPE_AGENT);
            }
        }
    }
    p3 = p2; p2 = bst;
    hb_m2 = hb_m1; hb_m1 = hb;

    // ---- collapse branch d=bst; record out bit; rebranch over c=P[u] ----
    bool sprv = bst ? psB : psA;                   // actual spike(u-1)
    bool sc0  = bst ? s10 : s00;                   // spike under c=0
    bool sc1  = bst ? s11 : s01;                   // spike under c=1
    float mc0 = bst ? m10 : m00;
    float mc1 = bst ? m11 : m01;

    if (u >= 1) {
        int v = u - 1;
        if ((v & 63) == lane) myb |= (sprv ? 1u : 0u) << (v >> 6);
    }

    memA = sc0 ? 0.0f : mc0;
    memB = sc1 ? 0.0f : mc1;

    // ---- merged if-converted updates (value-exact, no branches) ----
    float s0f = sc0 ? 1.0f : 0.0f;
    float s1f = sc1 ? 1.0f : 0.0f;
    float d0f = (!sc0 && sprv) ? 1.0f : 0.0f;      // mutually exclusive
    float d1f = (!sc1 && sprv) ? 1.0f : 0.0f;
    #pragma unroll
    for (int j = 0; j < CPL; ++j) {
        float base = bst ? wB[j] : wA[j];          // wB==wA when agreed
        float ta = fminf(fmaf(s0f, pfc[j], base), 127.0f);
        wA[j] = fmaxf(fmaf(-d0f, xfc[j], ta), 0.0f);
        float tb = fminf(fmaf(s1f, pfc[j], base), 127.0f);
        wB[j] = fmaxf(fmaf(-d1f, xfc[j], tb), 0.0f);
    }
    psA = sc0; psB = sc1;
}

__global__ __launch_bounds__(128, 1) void snn_kernel(const float* __restrict__ weight,
                                                     const uint8_t* __restrict__ code,
                                                     uint8_t* __restrict__ slots,
                                                     float* __restrict__ out) {
    const int tid  = threadIdx.x;
    const int wave = tid >> 6;
    const int lane = tid & 63;
    const int row  = blockIdx.x * 2 + wave;    // 512 autonomous waves, 256 CUs

    float wA[CPL], wB[CPL];
    #pragma unroll
    for (int j = 0; j < CPL; ++j) {
        int col = lane * CPL + j;
        float v = (col < CIN) ? weight[row * CIN + col] : 0.0f;
        wA[j] = v; wB[j] = v;
    }

    const uint4* code4 = (const uint4*)code;

    float xf0[CPL], pf0[CPL], xf1[CPL], pf1[CPL];
    {
        uint4 c0 = code4[lane];
        decode_code(c0, xf0, pf0);
    }
    uint4 cwA = code4[64 + lane];
    uint4 cwB = make_uint4(0u, 0u, 0u, 0u);

    float memA = 0.0f, memB = 0.0f;
    bool  psA = true, psB = true;          // spike(-1)=true quirk
    int p2 = 0, p3 = 0;                    // actual P[u-2], P[u-3]
    int hb_m1 = 0, hb_m2 = 0;              // own row hb(u-1), hb(u-2)
    uint32_t myb = 0u;                     // out bits: step v when v%64==lane

    for (int u = 0; u < T_STEPS; u += 2) {
        snn_step(u,     row, lane, code4, slots, wA, wB,
                 xf0, pf0, xf1, pf1, cwA, cwB,
                 memA, memB, psA, psB, p2, p3, hb_m1, hb_m2, myb);
        snn_step(u + 1, row, lane, code4, slots, wA, wB,
                 xf1, pf1, xf0, pf0, cwB, cwA,
                 memA, memB, psA, psB, p2, p3, hb_m1, hb_m2, myb);
    }

    // ---- epilogue: resolve P[T-1], record last bit, write this row's out ----
    {
        const int kk = (p3 << 1) | p2;
        int cst;
        if (((hb_m2 >> kk) & 1) != 0) {
            cst = 1;                       // own row forced the OR
        } else {
            const unsigned long long* gl2 =
                (const unsigned long long*)(slots + (size_t)(T_STEPS - 2) * NROW);
            unsigned long long gv2;
            for (;;) {
                gv2 = __hip_atomic_load(&gl2[lane], __ATOMIC_RELAXED,
                                        __HIP_MEMORY_SCOPE_AGENT);
                bool anyset, allp;
                scan8(gv2, kk, anyset, allp);
                if (__any((int)anyset)) { cst = 1; break; }
                if (__all((int)allp)) { cst = 0; break; }
                __builtin_amdgcn_s_sleep(1);
            }
        }
        bool sr = cst ? psB : psA;
        {
            int v = T_STEPS - 1;
            if ((v & 63) == lane) myb |= (sr ? 1u : 0u) << (v >> 6);
        }
        // write this row's 1000 spike floats from the bit register
        #pragma unroll
        for (int b = 0; b < 16; ++b) {
            int s = b * 64 + lane;
            if (s < T_STEPS)
                out[(size_t)s * COUT + row] = (float)((myb >> b) & 1u);
        }
    }
}

extern "C" void kernel_launch(void* const* d_in, const int* in_sizes, int n_in,
                              void* d_out, int out_size, void* d_ws, size_t ws_size,
                              hipStream_t stream) {
    const int*   x      = (const int*)d_in[0];     // (T,1,CIN) int32
    const float* weight = (const float*)d_in[1];   // (COUT,CIN) f32
    float* out = (float*)d_out;                    // (T,1,COUT) f32

    uint8_t* slots = (uint8_t*)d_ws;
    uint8_t* code  = (uint8_t*)d_ws + CODE_OFFSET;

    int prep_threads = T_STEPS * 64;
    prep_kernel<<<(prep_threads + 255) / 256, 256, 0, stream>>>(x, code,
                                                                (uint2*)slots);
    snn_kernel<<<256, 128, 0, stream>>>(weight, code, slots, out);
}

// Round 4
// 1003.953 us; speedup vs baseline: 1.3859x; 1.0067x over previous
//
#include <hip/hip_runtime.h>
#include <stdint.h>

// Net_11587821765063: sequential SNN scan, T=1000 steps.
// Output = spike_out (T,1,COUT) float32 only; w / traces are not returned.
//
// Round 23 (session r3): r22 champion (964us dispatch) with the LAST LDS op
// removed from the step loop. r22 counters: ~2314 cy/step vs ~600 cy VALU
// issue; r19(2w/SIMD) == r22(1w/SIMD) pace -> latency-bound on the per-wave
// serial chain, and the only memory-pipe RTT on that chain was the stage-4
// ds_swizzle (~120cy dependent LDS latency + lgkm wait barrier every step).
// Replaced with a 2-op DPP sequence (update_dpp old/bank_mask trick):
//   t1 = update_dpp(old=v,  src=v, row_ror:4,  bank_mask 0b0101) ; l&4==0 get v[l^4]
//   t2 = update_dpp(old=t1, src=v, row_ror:12, bank_mask 0b1010) ; l&4==1 get v[l^4]
// -> t2[l] = v[l^4] for all lanes: SAME partner pairing, SAME add (v + t2),
// bitwise-equal butterfly. Kernel now touches no LDS at all.
// Everything else byte-identical to r22 (grid 256x128, x2 unroll, gated
// gather, publish format, scan8, retry loop).

#define T_STEPS 1000
#define CIN     784
#define COUT    512
#define CPL     13            // columns per lane (64*13 = 832 >= 784)
#define NROW    512           // one publish byte per row per step
#define VTHR_F   12500.0f
#define PROHIB_F 11250.0f

#define SLOTS_BYTES (T_STEPS * NROW)          // 512000 B
#define CODE_OFFSET 524288                    // 512 KiB >= 512000 B of slots

// ---- prep: zero slot bytes and pack per-(t,lane) 16-byte code slot:
// byte j (j<13) encodes col = lane*13+j: bit0 = x[t][col], bits[2:1] = p.
__global__ __launch_bounds__(256) void prep_kernel(const int* __restrict__ x,
                                                   uint8_t* __restrict__ code,
                                                   uint2* __restrict__ slots2) {
    int gid = blockIdx.x * blockDim.x + threadIdx.x;   // one per (t, lane)
    if (gid >= T_STEPS * 64) return;
    slots2[gid] = make_uint2(0u, 0u);                  // 64000 x 8B = 512000 B
    int t = gid >> 6;
    int lane = gid & 63;
    uint32_t wds[4] = {0u, 0u, 0u, 0u};
    #pragma unroll
    for (int j = 0; j < CPL; ++j) {
        int col = lane * CPL + j;
        uint32_t b = 0u;
        if (col < CIN) {
            int xc = x[t * CIN + col];
            int xp = (t > 0) ? x[(t - 1) * CIN + col] : 0;
            int p = xc ? 2 : ((t == 0) ? 1 : (xp ? 1 : 0));
            b = (uint32_t)((xc & 1) | (p << 1));
        }
        wds[j >> 2] |= b << ((j & 3) * 8);
    }
    ((uint4*)code)[gid] = make_uint4(wds[0], wds[1], wds[2], wds[3]);
}

// scan one gathered uint64 (8 row-bytes): present = high nibble 0xB;
// set = present && hypothesis bit kk.
__device__ __forceinline__ void scan8(unsigned long long gv, int kk,
                                      bool& anyset, bool& allp) {
    anyset = false; allp = true;
    #pragma unroll
    for (int i = 0; i < 8; ++i) {
        uint32_t b = (uint32_t)(gv >> (8 * i)) & 0xFFu;
        bool p = (b & 0xF0u) == 0xB0u;
        allp = allp && p;
        anyset = anyset || (p && (((b >> kk) & 1u) != 0u));
    }
}

__device__ __forceinline__ void decode_code(const uint4& c, float* xf, float* pf) {
    uint32_t cwd[4] = {c.x, c.y, c.z, c.w};
    #pragma unroll
    for (int j = 0; j < CPL; ++j) {
        uint32_t byte = (cwd[j >> 2] >> ((j & 3) * 8)) & 0xFFu;
        xf[j] = (float)(byte & 1u);
        pf[j] = (float)(byte >> 1);
    }
}

// ---- fast bit-exact butterfly building blocks ----
typedef unsigned uint2ev __attribute__((ext_vector_type(2)));

__device__ __forceinline__ float pl32_sum(float v) {
    unsigned a = __builtin_bit_cast(unsigned, v);
    unsigned b = a;
#if __has_builtin(__builtin_amdgcn_permlane32_swap)
    uint2ev r = __builtin_amdgcn_permlane32_swap(a, b, false, false);
    a = r.x; b = r.y;
#else
    asm volatile("v_permlane32_swap_b32 %0, %1" : "+v"(a), "+v"(b));
#endif
    return __builtin_bit_cast(float, a) + __builtin_bit_cast(float, b);
}

__device__ __forceinline__ float pl16_sum(float v) {
    unsigned a = __builtin_bit_cast(unsigned, v);
    unsigned b = a;
#if __has_builtin(__builtin_amdgcn_permlane16_swap)
    uint2ev r = __builtin_amdgcn_permlane16_swap(a, b, false, false);
    a = r.x; b = r.y;
#else
    asm volatile("v_permlane16_swap_b32 %0, %1" : "+v"(a), "+v"(b));
#endif
    return __builtin_bit_cast(float, a) + __builtin_bit_cast(float, b);
}

template <int CTRL>
__device__ __forceinline__ float dpp_xor_sum(float v) {
    int xi = __builtin_bit_cast(int, v);
    int t = __builtin_amdgcn_update_dpp(xi, xi, CTRL, 0xF, 0xF, false);
    return v + __builtin_bit_cast(float, t);
}

// stage 4 (xor4 within 16-lane rows) in pure DPP, no LDS:
//  t1: row_ror:4  (0x124), bank_mask 0b0101 -> lanes l&4==0 get v[l^4], rest old=v
//  t2: row_ror:12 (0x12C), bank_mask 0b1010 -> lanes l&4==1 get v[l^4], rest old=t1
// result t2[l] = v[l^4] for every lane; sum v + t2 pairs identically to the
// validated xor4 ds_swizzle stage (adds commuted only).
__device__ __forceinline__ float dpp_xor4_sum(float v) {
    int xi = __builtin_bit_cast(int, v);
    int t1 = __builtin_amdgcn_update_dpp(xi, xi, 0x124, 0xF, 0x5, false);
    int t2 = __builtin_amdgcn_update_dpp(t1, xi, 0x12C, 0xF, 0xA, false);
    return v + __builtin_bit_cast(float, t2);
}

// full 64-lane sum, pairing bit-identical to the validated 32,16,8,4,2,1
// xor butterfly (adds commuted only -> bitwise-equal results)
__device__ __forceinline__ float wave_sum(float v) {
    v = pl32_sum(v);                  // stage 32
    v = pl16_sum(v);                  // stage 16
    v = dpp_xor_sum<0x128>(v);        // stage 8: row_ror:8 == xor8
    v = dpp_xor4_sum(v);              // stage 4: DPP pair, no LDS
    v = dpp_xor_sum<0x4E>(v);         // stage 2: quad_perm [2,3,0,1]
    v = dpp_xor_sum<0xB1>(v);         // stage 1: quad_perm [1,0,3,2]
    return v;                         // every lane holds the full sum
}

// one SNN step; fully inlined; pipeline registers passed explicitly so the
// x2-unrolled caller swaps roles instead of rotating (no movs).
__device__ __forceinline__ void snn_step(
    int u, int row, int lane,
    const uint4* __restrict__ code4, uint8_t* __restrict__ slots,
    float (&wA)[CPL], float (&wB)[CPL],
    float (&xfc)[CPL], float (&pfc)[CPL],     // decoded planes for step u
    float (&xfn)[CPL], float (&pfn)[CPL],     // decode target (step u+1)
    uint4& cwn,                               // in: raw code for step u+1
    uint4& cwl,                               // out: loaded code for u+2
    float& memA, float& memB, bool& psA, bool& psB,
    int& p2, int& p3, int& hb_m1, int& hb_m2,
    uint32_t& myb)
{
    // ---- top-of-loop issues: code load for u+2, gated gather for u-2 ----
    cwl = (u + 2 < T_STEPS) ? code4[(size_t)(u + 2) * 64 + lane]
                            : make_uint4(0u, 0u, 0u, 0u);
    const int kk = (p3 << 1) | p2;                 // (P[u-3]<<1)|P[u-2]
    const bool selfdec = (u >= 2) && (((hb_m2 >> kk) & 1) != 0);
    const unsigned long long* gl =
        (const unsigned long long*)(slots + (size_t)(u >= 2 ? u - 2 : 0) * NROW);
    unsigned long long gv = 0xB0B0B0B0B0B0B0B0ull; // sentinel-passing dummy
    if (u >= 2 && !selfdec)
        gv = __hip_atomic_load(&gl[lane], __ATOMIC_RELAXED,
                               __HIP_MEMORY_SCOPE_AGENT);

    // ---- dots for both branches (validated per-lane order) ----
    float dA = 0.0f, dB = 0.0f;
    #pragma unroll
    for (int j = 0; j < CPL; ++j) {
        dA += xfc[j] * wA[j];          // exact: x in {0,1}
        dB += xfc[j] * wB[j];
    }

    // ---- fast butterfly: two independent chains, bit-exact pairing ----
    float dotA = wave_sum(dA);
    float dotB = wave_sum(dB);

    // ---- pipelined decode of step u+1's codes (off the w->dot chain) ----
    decode_code(cwn, xfn, pfn);

    // ---- 4 hypotheses (d = P[u-1] branch, c = P[u] branch) ----
    float sa = memA + dotA;            // reference op order
    float sb = memB + dotB;
    float m00 = fmaxf(sa, 0.0f),            m01 = fmaxf(sa - PROHIB_F, 0.0f);
    float m10 = fmaxf(sb, 0.0f),            m11 = fmaxf(sb - PROHIB_F, 0.0f);
    bool s00 = m00 >= VTHR_F, s01 = m01 >= VTHR_F;
    bool s10 = m10 >= VTHR_F, s11 = m11 >= VTHR_F;
    int hb = (s00 ? 1 : 0) | (s01 ? 2 : 0) | (s10 ? 4 : 0) | (s11 ? 8 : 0);

    // ---- publish own row's hb(u) immediately (fire-and-forget byte) ----
    if (lane == 0)
        __hip_atomic_store(&slots[(size_t)u * NROW + row],
                           (uint8_t)(0xB0u | (uint32_t)hb),
                           __ATOMIC_RELAXED, __HIP_MEMORY_SCOPE_AGENT);

    // ---- resolve P[u-1]: own-row selfdec (~88%) or global fallback ----
    int bst = 0;
    if (u >= 2) {
        if (selfdec) {
            bst = 1;                   // own row spiked at u-2
        } else {
            for (;;) {
                bool anyset, allp;
                scan8(gv, kk, anyset, allp);
                if (__any((int)anyset)) { bst = 1; break; }
                if (__all((int)allp)) { bst = 0; break; }
                __builtin_amdgcn_s_sleep(1);       // backoff (rare path)
                gv = __hip_atomic_load(&gl[lane], __ATOMIC_RELAXED,
                                       __HIP_MEMORY_SCOPE_AGENT);
            }
        }
    }
    p3 = p2; p2 = bst;
    hb_m2 = hb_m1; hb_m1 = hb;

    // ---- collapse branch d=bst; record out bit; rebranch over c=P[u] ----
    bool sprv = bst ? psB : psA;                   // actual spike(u-1)
    bool sc0  = bst ? s10 : s00;                   // spike under c=0
    bool sc1  = bst ? s11 : s01;                   // spike under c=1
    float mc0 = bst ? m10 : m00;
    float mc1 = bst ? m11 : m01;

    if (u >= 1) {
        int v = u - 1;
        if ((v & 63) == lane) myb |= (sprv ? 1u : 0u) << (v >> 6);
    }

    memA = sc0 ? 0.0f : mc0;
    memB = sc1 ? 0.0f : mc1;

    // ---- merged if-converted updates (value-exact, no branches) ----
    float s0f = sc0 ? 1.0f : 0.0f;
    float s1f = sc1 ? 1.0f : 0.0f;
    float d0f = (!sc0 && sprv) ? 1.0f : 0.0f;      // mutually exclusive
    float d1f = (!sc1 && sprv) ? 1.0f : 0.0f;
    #pragma unroll
    for (int j = 0; j < CPL; ++j) {
        float base = bst ? wB[j] : wA[j];          // wB==wA when agreed
        float ta = fminf(fmaf(s0f, pfc[j], base), 127.0f);
        wA[j] = fmaxf(fmaf(-d0f, xfc[j], ta), 0.0f);
        float tb = fminf(fmaf(s1f, pfc[j], base), 127.0f);
        wB[j] = fmaxf(fmaf(-d1f, xfc[j], tb), 0.0f);
    }
    psA = sc0; psB = sc1;
}

__global__ __launch_bounds__(128, 1) void snn_kernel(const float* __restrict__ weight,
                                                     const uint8_t* __restrict__ code,
                                                     uint8_t* __restrict__ slots,
                                                     float* __restrict__ out) {
    const int tid  = threadIdx.x;
    const int wave = tid >> 6;
    const int lane = tid & 63;
    const int row  = blockIdx.x * 2 + wave;    // 512 autonomous waves, 256 CUs

    float wA[CPL], wB[CPL];
    #pragma unroll
    for (int j = 0; j < CPL; ++j) {
        int col = lane * CPL + j;
        float v = (col < CIN) ? weight[row * CIN + col] : 0.0f;
        wA[j] = v; wB[j] = v;
    }

    const uint4* code4 = (const uint4*)code;

    float xf0[CPL], pf0[CPL], xf1[CPL], pf1[CPL];
    {
        uint4 c0 = code4[lane];
        decode_code(c0, xf0, pf0);
    }
    uint4 cwA = code4[64 + lane];
    uint4 cwB = make_uint4(0u, 0u, 0u, 0u);

    float memA = 0.0f, memB = 0.0f;
    bool  psA = true, psB = true;          // spike(-1)=true quirk
    int p2 = 0, p3 = 0;                    // actual P[u-2], P[u-3]
    int hb_m1 = 0, hb_m2 = 0;              // own row hb(u-1), hb(u-2)
    uint32_t myb = 0u;                     // out bits: step v when v%64==lane

    for (int u = 0; u < T_STEPS; u += 2) {
        snn_step(u,     row, lane, code4, slots, wA, wB,
                 xf0, pf0, xf1, pf1, cwA, cwB,
                 memA, memB, psA, psB, p2, p3, hb_m1, hb_m2, myb);
        snn_step(u + 1, row, lane, code4, slots, wA, wB,
                 xf1, pf1, xf0, pf0, cwB, cwA,
                 memA, memB, psA, psB, p2, p3, hb_m1, hb_m2, myb);
    }

    // ---- epilogue: resolve P[T-1], record last bit, write this row's out ----
    {
        const int kk = (p3 << 1) | p2;
        int cst;
        if (((hb_m2 >> kk) & 1) != 0) {
            cst = 1;                       // own row forced the OR
        } else {
            const unsigned long long* gl2 =
                (const unsigned long long*)(slots + (size_t)(T_STEPS - 2) * NROW);
            unsigned long long gv2;
            for (;;) {
                gv2 = __hip_atomic_load(&gl2[lane], __ATOMIC_RELAXED,
                                        __HIP_MEMORY_SCOPE_AGENT);
                bool anyset, allp;
                scan8(gv2, kk, anyset, allp);
                if (__any((int)anyset)) { cst = 1; break; }
                if (__all((int)allp)) { cst = 0; break; }
                __builtin_amdgcn_s_sleep(1);
            }
        }
        bool sr = cst ? psB : psA;
        {
            int v = T_STEPS - 1;
            if ((v & 63) == lane) myb |= (sr ? 1u : 0u) << (v >> 6);
        }
        // write this row's 1000 spike floats from the bit register
        #pragma unroll
        for (int b = 0; b < 16; ++b) {
            int s = b * 64 + lane;
            if (s < T_STEPS)
                out[(size_t)s * COUT + row] = (float)((myb >> b) & 1u);
        }
    }
}

extern "C" void kernel_launch(void* const* d_in, const int* in_sizes, int n_in,
                              void* d_out, int out_size, void* d_ws, size_t ws_size,
                              hipStream_t stream) {
    const int*   x      = (const int*)d_in[0];     // (T,1,CIN) int32
    const float* weight = (const float*)d_in[1];   // (COUT,CIN) f32
    float* out = (float*)d_out;                    // (T,1,COUT) f32

    uint8_t* slots = (uint8_t*)d_ws;
    uint8_t* code  = (uint8_t*)d_ws + CODE_OFFSET;

    int prep_threads = T_STEPS * 64;
    prep_kernel<<<(prep_threads + 255) / 256, 256, 0, stream>>>(x, code,
                                                                (uint2*)slots);
    snn_kernel<<<256, 128, 0, stream>>>(weight, code, slots, out);
}

// Round 5
// 945.679 us; speedup vs baseline: 1.4713x; 1.0616x over previous
//
#include <hip/hip_runtime.h>
#include <stdint.h>

// Net_11587821765063: sequential SNN scan, T=1000 steps.
// Output = spike_out (T,1,COUT) float32 only; w / traces are not returned.
//
// Round 24 (session r4): r23 (958us dispatch) post-mortem says local latency
// is NOT the pace: 3 structural rounds moved only ~9%. Revised model: pace =
// (V + 400cy)/3 where V is publish->remote-visible latency; measured pace
// 2300cy/step -> V ~= 6500cy. Counter evidence for HOT-LINE STORE
// SERIALIZATION: WRITE_SIZE 22MB for 512KB of slot bytes (byte-stores write
// through unmerged), and each step's 512 slot bytes sit in only 8 lines ->
// 64 serialized remote stores/line (~100cy each ~= 6400cy) before a reader's
// allp can pass.
// EXPERIMENT: stride each row's slot to 8B -> 64 lines/step, 8 stores/line.
// Reader: 8x 8B agent loads per lane (RTT-overlapped), byte0 per row; same
// predicate, same publish byte, same retry loop -> bit-exact by layout
// independence. Workspace needs 5.2MB -> gated on ws_size at launch; if too
// small, runs the r23 champion VERBATIM (narrow template instantiation).
// All arithmetic (13-FMA dot order, 32/16/8/4/2/1 DPP butterfly, hypotheses,
// updates, publish format 0xB0|hb, scan semantics) byte-identical to r23.

#define T_STEPS 1000
#define CIN     784
#define COUT    512
#define CPL     13            // columns per lane (64*13 = 832 >= 784)
#define VTHR_F   12500.0f
#define PROHIB_F 11250.0f

// narrow (proven r23) layout
#define N_NROW        512                     // 1B per row per step
#define N_CODE_OFFSET 524288                  // 512 KiB >= 512000 B of slots
// wide (experimental) layout
#define W_ROWBYTES    4096                    // 512 rows * 8B stride
#define W_CODE_OFFSET 4194304                 // 4 MiB >= 4,096,000 B of slots
#define CODE_BYTES    (T_STEPS * 64 * 16)     // 1,024,000 B
#define W_TOTAL       ((size_t)W_CODE_OFFSET + (size_t)CODE_BYTES)

// ---- prep: zero slot bytes and pack per-(t,lane) 16-byte code slot:
// byte j (j<13) encodes col = lane*13+j: bit0 = x[t][col], bits[2:1] = p.
template <bool WIDE>
__global__ __launch_bounds__(256) void prep_kernel(const int* __restrict__ x,
                                                   uint8_t* __restrict__ code,
                                                   uint8_t* __restrict__ slots) {
    int gid = blockIdx.x * blockDim.x + threadIdx.x;   // one per (t, lane)
    if (gid >= T_STEPS * 64) return;
    if constexpr (WIDE) {
        uint4 z = make_uint4(0u, 0u, 0u, 0u);
        uint4* s4 = (uint4*)slots;                      // 64000 x 64B = 4.096MB
        #pragma unroll
        for (int k = 0; k < 4; ++k) s4[(size_t)gid * 4 + k] = z;
    } else {
        ((uint2*)slots)[gid] = make_uint2(0u, 0u);      // 64000 x 8B = 512000 B
    }
    int t = gid >> 6;
    int lane = gid & 63;
    uint32_t wds[4] = {0u, 0u, 0u, 0u};
    #pragma unroll
    for (int j = 0; j < CPL; ++j) {
        int col = lane * CPL + j;
        uint32_t b = 0u;
        if (col < CIN) {
            int xc = x[t * CIN + col];
            int xp = (t > 0) ? x[(t - 1) * CIN + col] : 0;
            int p = xc ? 2 : ((t == 0) ? 1 : (xp ? 1 : 0));
            b = (uint32_t)((xc & 1) | (p << 1));
        }
        wds[j >> 2] |= b << ((j & 3) * 8);
    }
    ((uint4*)code)[gid] = make_uint4(wds[0], wds[1], wds[2], wds[3]);
}

// scan one gathered uint64 (8 row-bytes, narrow): present = high nibble 0xB;
// set = present && hypothesis bit kk.
__device__ __forceinline__ void scan8(unsigned long long gv, int kk,
                                      bool& anyset, bool& allp) {
    anyset = false; allp = true;
    #pragma unroll
    for (int i = 0; i < 8; ++i) {
        uint32_t b = (uint32_t)(gv >> (8 * i)) & 0xFFu;
        bool p = (b & 0xF0u) == 0xB0u;
        allp = allp && p;
        anyset = anyset || (p && (((b >> kk) & 1u) != 0u));
    }
}

// wide: 8 slots (8B stride), row byte is byte0 of each ull; same predicate.
__device__ __forceinline__ void scan8w(const unsigned long long* g, int kk,
                                       bool& anyset, bool& allp) {
    anyset = false; allp = true;
    #pragma unroll
    for (int i = 0; i < 8; ++i) {
        uint32_t b = (uint32_t)(g[i] & 0xFFu);
        bool p = (b & 0xF0u) == 0xB0u;
        allp = allp && p;
        anyset = anyset || (p && (((b >> kk) & 1u) != 0u));
    }
}

__device__ __forceinline__ void decode_code(const uint4& c, float* xf, float* pf) {
    uint32_t cwd[4] = {c.x, c.y, c.z, c.w};
    #pragma unroll
    for (int j = 0; j < CPL; ++j) {
        uint32_t byte = (cwd[j >> 2] >> ((j & 3) * 8)) & 0xFFu;
        xf[j] = (float)(byte & 1u);
        pf[j] = (float)(byte >> 1);
    }
}

// ---- fast bit-exact butterfly building blocks ----
typedef unsigned uint2ev __attribute__((ext_vector_type(2)));

__device__ __forceinline__ float pl32_sum(float v) {
    unsigned a = __builtin_bit_cast(unsigned, v);
    unsigned b = a;
#if __has_builtin(__builtin_amdgcn_permlane32_swap)
    uint2ev r = __builtin_amdgcn_permlane32_swap(a, b, false, false);
    a = r.x; b = r.y;
#else
    asm volatile("v_permlane32_swap_b32 %0, %1" : "+v"(a), "+v"(b));
#endif
    return __builtin_bit_cast(float, a) + __builtin_bit_cast(float, b);
}

__device__ __forceinline__ float pl16_sum(float v) {
    unsigned a = __builtin_bit_cast(unsigned, v);
    unsigned b = a;
#if __has_builtin(__builtin_amdgcn_permlane16_swap)
    uint2ev r = __builtin_amdgcn_permlane16_swap(a, b, false, false);
    a = r.x; b = r.y;
#else
    asm volatile("v_permlane16_swap_b32 %0, %1" : "+v"(a), "+v"(b));
#endif
    return __builtin_bit_cast(float, a) + __builtin_bit_cast(float, b);
}

template <int CTRL>
__device__ __forceinline__ float dpp_xor_sum(float v) {
    int xi = __builtin_bit_cast(int, v);
    int t = __builtin_amdgcn_update_dpp(xi, xi, CTRL, 0xF, 0xF, false);
    return v + __builtin_bit_cast(float, t);
}

// stage 4 (xor4 within 16-lane rows) in pure DPP, no LDS (validated r23):
__device__ __forceinline__ float dpp_xor4_sum(float v) {
    int xi = __builtin_bit_cast(int, v);
    int t1 = __builtin_amdgcn_update_dpp(xi, xi, 0x124, 0xF, 0x5, false);
    int t2 = __builtin_amdgcn_update_dpp(t1, xi, 0x12C, 0xF, 0xA, false);
    return v + __builtin_bit_cast(float, t2);
}

// full 64-lane sum, pairing bit-identical to the validated 32,16,8,4,2,1
// xor butterfly (adds commuted only -> bitwise-equal results)
__device__ __forceinline__ float wave_sum(float v) {
    v = pl32_sum(v);                  // stage 32
    v = pl16_sum(v);                  // stage 16
    v = dpp_xor_sum<0x128>(v);        // stage 8: row_ror:8 == xor8
    v = dpp_xor4_sum(v);              // stage 4: DPP pair, no LDS
    v = dpp_xor_sum<0x4E>(v);         // stage 2: quad_perm [2,3,0,1]
    v = dpp_xor_sum<0xB1>(v);         // stage 1: quad_perm [1,0,3,2]
    return v;                         // every lane holds the full sum
}

// one SNN step; fully inlined; pipeline registers passed explicitly so the
// x2-unrolled caller swaps roles instead of rotating (no movs).
template <bool WIDE>
__device__ __forceinline__ void snn_step(
    int u, int row, int lane,
    const uint4* __restrict__ code4, uint8_t* __restrict__ slots,
    float (&wA)[CPL], float (&wB)[CPL],
    float (&xfc)[CPL], float (&pfc)[CPL],     // decoded planes for step u
    float (&xfn)[CPL], float (&pfn)[CPL],     // decode target (step u+1)
    uint4& cwn,                               // in: raw code for step u+1
    uint4& cwl,                               // out: loaded code for u+2
    float& memA, float& memB, bool& psA, bool& psB,
    int& p2, int& p3, int& hb_m1, int& hb_m2,
    uint32_t& myb)
{
    // ---- top-of-loop issues: code load for u+2, gated gather for u-2 ----
    cwl = (u + 2 < T_STEPS) ? code4[(size_t)(u + 2) * 64 + lane]
                            : make_uint4(0u, 0u, 0u, 0u);
    const int kk = (p3 << 1) | p2;                 // (P[u-3]<<1)|P[u-2]
    const bool selfdec = (u >= 2) && (((hb_m2 >> kk) & 1) != 0);

    const unsigned long long* gl;
    unsigned long long gv = 0xB0B0B0B0B0B0B0B0ull; // narrow: sentinel dummy
    unsigned long long g[8];
    if constexpr (WIDE) {
        gl = (const unsigned long long*)
             (slots + (size_t)(u >= 2 ? u - 2 : 0) * W_ROWBYTES);
        #pragma unroll
        for (int i = 0; i < 8; ++i) g[i] = 0xB0B0B0B0B0B0B0B0ull;
        if (u >= 2 && !selfdec) {
            #pragma unroll
            for (int i = 0; i < 8; ++i)
                g[i] = __hip_atomic_load(&gl[8 * lane + i], __ATOMIC_RELAXED,
                                         __HIP_MEMORY_SCOPE_AGENT);
        }
    } else {
        gl = (const unsigned long long*)
             (slots + (size_t)(u >= 2 ? u - 2 : 0) * N_NROW);
        if (u >= 2 && !selfdec)
            gv = __hip_atomic_load(&gl[lane], __ATOMIC_RELAXED,
                                   __HIP_MEMORY_SCOPE_AGENT);
    }

    // ---- dots for both branches (validated per-lane order) ----
    float dA = 0.0f, dB = 0.0f;
    #pragma unroll
    for (int j = 0; j < CPL; ++j) {
        dA += xfc[j] * wA[j];          // exact: x in {0,1}
        dB += xfc[j] * wB[j];
    }

    // ---- fast butterfly: two independent chains, bit-exact pairing ----
    float dotA = wave_sum(dA);
    float dotB = wave_sum(dB);

    // ---- pipelined decode of step u+1's codes (off the w->dot chain) ----
    decode_code(cwn, xfn, pfn);

    // ---- 4 hypotheses (d = P[u-1] branch, c = P[u] branch) ----
    float sa = memA + dotA;            // reference op order
    float sb = memB + dotB;
    float m00 = fmaxf(sa, 0.0f),            m01 = fmaxf(sa - PROHIB_F, 0.0f);
    float m10 = fmaxf(sb, 0.0f),            m11 = fmaxf(sb - PROHIB_F, 0.0f);
    bool s00 = m00 >= VTHR_F, s01 = m01 >= VTHR_F;
    bool s10 = m10 >= VTHR_F, s11 = m11 >= VTHR_F;
    int hb = (s00 ? 1 : 0) | (s01 ? 2 : 0) | (s10 ? 4 : 0) | (s11 ? 8 : 0);

    // ---- publish own row's hb(u) immediately (fire-and-forget byte) ----
    if (lane == 0) {
        size_t addr = WIDE ? ((size_t)u * W_ROWBYTES + (size_t)row * 8)
                           : ((size_t)u * N_NROW + (size_t)row);
        __hip_atomic_store(&slots[addr], (uint8_t)(0xB0u | (uint32_t)hb),
                           __ATOMIC_RELAXED, __HIP_MEMORY_SCOPE_AGENT);
    }

    // ---- resolve P[u-1]: own-row selfdec (~88%) or global fallback ----
    int bst = 0;
    if (u >= 2) {
        if (selfdec) {
            bst = 1;                   // own row spiked at u-2
        } else {
            for (;;) {
                bool anyset, allp;
                if constexpr (WIDE) scan8w(g, kk, anyset, allp);
                else                scan8(gv, kk, anyset, allp);
                if (__any((int)anyset)) { bst = 1; break; }
                if (__all((int)allp)) { bst = 0; break; }
                __builtin_amdgcn_s_sleep(1);       // backoff (rare path)
                if constexpr (WIDE) {
                    #pragma unroll
                    for (int i = 0; i < 8; ++i)
                        g[i] = __hip_atomic_load(&gl[8 * lane + i],
                                                 __ATOMIC_RELAXED,
                                                 __HIP_MEMORY_SCOPE_AGENT);
                } else {
                    gv = __hip_atomic_load(&gl[lane], __ATOMIC_RELAXED,
                                           __HIP_MEMORY_SCOPE_AGENT);
                }
            }
        }
    }
    p3 = p2; p2 = bst;
    hb_m2 = hb_m1; hb_m1 = hb;

    // ---- collapse branch d=bst; record out bit; rebranch over c=P[u] ----
    bool sprv = bst ? psB : psA;                   // actual spike(u-1)
    bool sc0  = bst ? s10 : s00;                   // spike under c=0
    bool sc1  = bst ? s11 : s01;                   // spike under c=1
    float mc0 = bst ? m10 : m00;
    float mc1 = bst ? m11 : m01;

    if (u >= 1) {
        int v = u - 1;
        if ((v & 63) == lane) myb |= (sprv ? 1u : 0u) << (v >> 6);
    }

    memA = sc0 ? 0.0f : mc0;
    memB = sc1 ? 0.0f : mc1;

    // ---- merged if-converted updates (value-exact, no branches) ----
    float s0f = sc0 ? 1.0f : 0.0f;
    float s1f = sc1 ? 1.0f : 0.0f;
    float d0f = (!sc0 && sprv) ? 1.0f : 0.0f;      // mutually exclusive
    float d1f = (!sc1 && sprv) ? 1.0f : 0.0f;
    #pragma unroll
    for (int j = 0; j < CPL; ++j) {
        float base = bst ? wB[j] : wA[j];          // wB==wA when agreed
        float ta = fminf(fmaf(s0f, pfc[j], base), 127.0f);
        wA[j] = fmaxf(fmaf(-d0f, xfc[j], ta), 0.0f);
        float tb = fminf(fmaf(s1f, pfc[j], base), 127.0f);
        wB[j] = fmaxf(fmaf(-d1f, xfc[j], tb), 0.0f);
    }
    psA = sc0; psB = sc1;
}

template <bool WIDE>
__global__ __launch_bounds__(128, 1) void snn_kernel(const float* __restrict__ weight,
                                                     const uint8_t* __restrict__ code,
                                                     uint8_t* __restrict__ slots,
                                                     float* __restrict__ out) {
    const int tid  = threadIdx.x;
    const int wave = tid >> 6;
    const int lane = tid & 63;
    const int row  = blockIdx.x * 2 + wave;    // 512 autonomous waves, 256 CUs

    float wA[CPL], wB[CPL];
    #pragma unroll
    for (int j = 0; j < CPL; ++j) {
        int col = lane * CPL + j;
        float v = (col < CIN) ? weight[row * CIN + col] : 0.0f;
        wA[j] = v; wB[j] = v;
    }

    const uint4* code4 = (const uint4*)code;

    float xf0[CPL], pf0[CPL], xf1[CPL], pf1[CPL];
    {
        uint4 c0 = code4[lane];
        decode_code(c0, xf0, pf0);
    }
    uint4 cwA = code4[64 + lane];
    uint4 cwB = make_uint4(0u, 0u, 0u, 0u);

    float memA = 0.0f, memB = 0.0f;
    bool  psA = true, psB = true;          // spike(-1)=true quirk
    int p2 = 0, p3 = 0;                    // actual P[u-2], P[u-3]
    int hb_m1 = 0, hb_m2 = 0;              // own row hb(u-1), hb(u-2)
    uint32_t myb = 0u;                     // out bits: step v when v%64==lane

    for (int u = 0; u < T_STEPS; u += 2) {
        snn_step<WIDE>(u,     row, lane, code4, slots, wA, wB,
                       xf0, pf0, xf1, pf1, cwA, cwB,
                       memA, memB, psA, psB, p2, p3, hb_m1, hb_m2, myb);
        snn_step<WIDE>(u + 1, row, lane, code4, slots, wA, wB,
                       xf1, pf1, xf0, pf0, cwB, cwA,
                       memA, memB, psA, psB, p2, p3, hb_m1, hb_m2, myb);
    }

    // ---- epilogue: resolve P[T-1], record last bit, write this row's out ----
    {
        const int kk = (p3 << 1) | p2;
        int cst;
        if (((hb_m2 >> kk) & 1) != 0) {
            cst = 1;                       // own row forced the OR
        } else if constexpr (WIDE) {
            const unsigned long long* gl2 =
                (const unsigned long long*)(slots + (size_t)(T_STEPS - 2) * W_ROWBYTES);
            unsigned long long g2[8];
            for (;;) {
                #pragma unroll
                for (int i = 0; i < 8; ++i)
                    g2[i] = __hip_atomic_load(&gl2[8 * lane + i],
                                              __ATOMIC_RELAXED,
                                              __HIP_MEMORY_SCOPE_AGENT);
                bool anyset, allp;
                scan8w(g2, kk, anyset, allp);
                if (__any((int)anyset)) { cst = 1; break; }
                if (__all((int)allp)) { cst = 0; break; }
                __builtin_amdgcn_s_sleep(1);
            }
        } else {
            const unsigned long long* gl2 =
                (const unsigned long long*)(slots + (size_t)(T_STEPS - 2) * N_NROW);
            unsigned long long gv2;
            for (;;) {
                gv2 = __hip_atomic_load(&gl2[lane], __ATOMIC_RELAXED,
                                        __HIP_MEMORY_SCOPE_AGENT);
                bool anyset, allp;
                scan8(gv2, kk, anyset, allp);
                if (__any((int)anyset)) { cst = 1; break; }
                if (__all((int)allp)) { cst = 0; break; }
                __builtin_amdgcn_s_sleep(1);
            }
        }
        bool sr = cst ? psB : psA;
        {
            int v = T_STEPS - 1;
            if ((v & 63) == lane) myb |= (sr ? 1u : 0u) << (v >> 6);
        }
        // write this row's 1000 spike floats from the bit register
        #pragma unroll
        for (int b = 0; b < 16; ++b) {
            int s = b * 64 + lane;
            if (s < T_STEPS)
                out[(size_t)s * COUT + row] = (float)((myb >> b) & 1u);
        }
    }
}

extern "C" void kernel_launch(void* const* d_in, const int* in_sizes, int n_in,
                              void* d_out, int out_size, void* d_ws, size_t ws_size,
                              hipStream_t stream) {
    const int*   x      = (const int*)d_in[0];     // (T,1,CIN) int32
    const float* weight = (const float*)d_in[1];   // (COUT,CIN) f32
    float* out = (float*)d_out;                    // (T,1,COUT) f32

    int prep_threads = T_STEPS * 64;
    if (ws_size >= W_TOTAL) {
        // wide layout: 8B/row slots (64 lines/step, 8 stores/line)
        uint8_t* slots = (uint8_t*)d_ws;
        uint8_t* code  = (uint8_t*)d_ws + W_CODE_OFFSET;
        prep_kernel<true><<<(prep_threads + 255) / 256, 256, 0, stream>>>(
            x, code, slots);
        snn_kernel<true><<<256, 128, 0, stream>>>(weight, code, slots, out);
    } else {
        // narrow layout: proven r23 envelope (1,548,288 B)
        uint8_t* slots = (uint8_t*)d_ws;
        uint8_t* code  = (uint8_t*)d_ws + N_CODE_OFFSET;
        prep_kernel<false><<<(prep_threads + 255) / 256, 256, 0, stream>>>(
            x, code, slots);
        snn_kernel<false><<<256, 128, 0, stream>>>(weight, code, slots, out);
    }
}